// Round 9
// baseline (22.193 us; speedup 1.0000x reference)
//
#include <hip/hip_runtime.h>
#include <hip/hip_bf16.h>

// Problem constants (match reference)
#define VOCAB 50000
#define BB 64
#define TT 512
#define CC 512
#define HALF 50
#define WW 101            // window = 2*HALF+1
#define ROWS (BB * TT)    // 32768 rows, one wave each (R8 structure: best = 20.9us)

typedef float vfloat4 __attribute__((ext_vector_type(4)));

// Wave64 sum via DPP: row_shr 1,2,4,8 then row_bcast 15,31 (rocPRIM pattern).
template <int CTRL>
__device__ __forceinline__ float dpp_add_step(float x) {
    int t = __builtin_amdgcn_update_dpp(0, __float_as_int(x), CTRL, 0xf, 0xf, false);
    return x + __int_as_float(t);
}

__global__ __launch_bounds__(256) void TimeAttention_38345468019460_kernel(
    const int*   __restrict__ concepts,   // [B*T]
    const int*   __restrict__ tts,        // [B*T]
    const int*   __restrict__ cts,        // [B*C]
    const int*   __restrict__ mask,       // [B*C]
    const float* __restrict__ emb,        // [VOCAB*W]
    float*       __restrict__ out)        // [B*T*C]
{
    const int wid  = threadIdx.x >> 6;          // wave index within block (0..3)
    const int lane = threadIdx.x & 63;
    // row is wave-uniform: pin it to an SGPR so concept/timestamp loads scalarize
    const int row  = __builtin_amdgcn_readfirstlane((blockIdx.x << 2) + wid);
    const int b    = row >> 9;                  // T = 512
    const int tadj    = tts[row] - HALF;        // fold +HALF into the clamp
    const int concept = concepts[row];

    // Stage this row's 101-float embedding window into a WAVE-PRIVATE LDS slab.
    __shared__ float semb[4][104];
    const float* erow = emb + (long)concept * WW;
    semb[wid][lane] = erow[lane];                                // lanes 0..63
    if (lane < WW - 64) semb[wid][lane + 64] = erow[lane + 64];  // lanes 0..36
    __builtin_amdgcn_wave_barrier();  // wave-private region: no block barrier

    // Each lane handles 8 contiguous context slots.
    const int cbase = b * CC + lane * 8;
    int4 ct0 = *(const int4*)(cts  + cbase);
    int4 ct1 = *(const int4*)(cts  + cbase + 4);
    int4 mk0 = *(const int4*)(mask + cbase);
    int4 mk1 = *(const int4*)(mask + cbase + 4);

    int cc[8] = {ct0.x, ct0.y, ct0.z, ct0.w, ct1.x, ct1.y, ct1.z, ct1.w};
    int mm[8] = {mk0.x, mk0.y, mk0.z, mk0.w, mk1.x, mk1.y, mk1.z, mk1.w};

    // No-max softmax (validated: absmax 2.4e-4): masked -> exp(-1e9) = 0.
    float p[8];
    float s = 0.0f;
    #pragma unroll
    for (int j = 0; j < 8; ++j) {
        int d = cc[j] - tadj;
        d = min(max(d, 0), WW - 1);                    // v_sub + v_med3
        float v = semb[wid][d] + (float)mm[j] * (-1e9f);
        p[j] = __expf(v);
        s += p[j];
    }

    // Wave-wide sum: DPP chain, total in lane 63, broadcast via readlane.
    s = dpp_add_step<0x111>(s);   // row_shr:1
    s = dpp_add_step<0x112>(s);   // row_shr:2
    s = dpp_add_step<0x114>(s);   // row_shr:4
    s = dpp_add_step<0x118>(s);   // row_shr:8
    s = dpp_add_step<0x142>(s);   // row_bcast:15
    s = dpp_add_step<0x143>(s);   // row_bcast:31
    const float stot = __int_as_float(__builtin_amdgcn_readlane(__float_as_int(s), 63));

    const float inv = __builtin_amdgcn_rcpf(stot);
    vfloat4 o0 = {p[0] * inv, p[1] * inv, p[2] * inv, p[3] * inv};
    vfloat4 o1 = {p[4] * inv, p[5] * inv, p[6] * inv, p[7] * inv};

    // A/B vs R8: PLAIN stores (no nt) — let L2 aggregate the write stream,
    // matching the 6.3 TB/s fill kernel's store path.
    const long obase = (long)row * CC + lane * 8;
    *(vfloat4*)(out + obase)     = o0;
    *(vfloat4*)(out + obase + 4) = o1;
}

extern "C" void kernel_launch(void* const* d_in, const int* in_sizes, int n_in,
                              void* d_out, int out_size, void* d_ws, size_t ws_size,
                              hipStream_t stream) {
    const int*   concepts = (const int*)d_in[0];
    const int*   tts      = (const int*)d_in[1];
    const int*   cts      = (const int*)d_in[2];
    const int*   mask     = (const int*)d_in[3];
    const float* emb      = (const float*)d_in[4];
    float*       out      = (float*)d_out;

    const int blocks = ROWS / 4;   // 8192 blocks, 4 waves (rows) each
    TimeAttention_38345468019460_kernel<<<blocks, 256, 0, stream>>>(
        concepts, tts, cts, mask, emb, out);
}

// Round 10
// 16.839 us; speedup vs baseline: 1.3179x; 1.3179x over previous
//
#include <hip/hip_runtime.h>
#include <hip/hip_bf16.h>

// Problem constants (match reference)
#define VOCAB 50000
#define BB 64
#define TT 512
#define CC 512
#define HALF 50
#define WW 101            // window = 2*HALF+1
#define ROWS (BB * TT)    // 32768 rows, one wave each (R8 structure: best = 20.9us)

typedef float vfloat4 __attribute__((ext_vector_type(4)));

// Wave64 sum via DPP: row_shr 1,2,4,8 then row_bcast 15,31 (rocPRIM pattern).
template <int CTRL>
__device__ __forceinline__ float dpp_add_step(float x) {
    int t = __builtin_amdgcn_update_dpp(0, __float_as_int(x), CTRL, 0xf, 0xf, false);
    return x + __int_as_float(t);
}

__global__ __launch_bounds__(256) void TimeAttention_38345468019460_kernel(
    const int*   __restrict__ concepts,   // [B*T]
    const int*   __restrict__ tts,        // [B*T]
    const int*   __restrict__ cts,        // [B*C]
    const int*   __restrict__ mask,       // [B*C]
    const float* __restrict__ emb,        // [VOCAB*W]
    float*       __restrict__ out)        // [B*T*C]
{
    const int wid  = threadIdx.x >> 6;          // wave index within block (0..3)
    const int lane = threadIdx.x & 63;
    // row is wave-uniform: pin it to an SGPR so concept/timestamp loads scalarize
    const int row  = __builtin_amdgcn_readfirstlane((blockIdx.x << 2) + wid);
    const int b    = row >> 9;                  // T = 512
    const int tadj    = tts[row] - HALF;        // fold +HALF into the clamp
    const int concept = concepts[row];

    // Stage this row's 101-float embedding window into a WAVE-PRIVATE LDS slab.
    __shared__ float semb[4][104];
    const float* erow = emb + (long)concept * WW;
    semb[wid][lane] = erow[lane];                                // lanes 0..63
    if (lane < WW - 64) semb[wid][lane + 64] = erow[lane + 64];  // lanes 0..36
    __builtin_amdgcn_wave_barrier();  // wave-private region: no block barrier

    // Each lane owns 4 CONTIGUOUS slots in each half-row:
    // [lane*4, lane*4+4) and [256+lane*4, ...). Every wave load/store
    // instruction is then a fully-contiguous 1KB burst (vs 50%-density
    // 2KB span with the lane*8 layout).
    const int cbase0 = b * CC + lane * 4;
    int4 ct0 = *(const int4*)(cts  + cbase0);
    int4 ct1 = *(const int4*)(cts  + cbase0 + 256);
    int4 mk0 = *(const int4*)(mask + cbase0);
    int4 mk1 = *(const int4*)(mask + cbase0 + 256);

    int cc[8] = {ct0.x, ct0.y, ct0.z, ct0.w, ct1.x, ct1.y, ct1.z, ct1.w};
    int mm[8] = {mk0.x, mk0.y, mk0.z, mk0.w, mk1.x, mk1.y, mk1.z, mk1.w};

    // No-max softmax (validated: absmax 2.4e-4): masked -> exp(-1e9) = 0.
    float p[8];
    float s = 0.0f;
    #pragma unroll
    for (int j = 0; j < 8; ++j) {
        int d = cc[j] - tadj;
        d = min(max(d, 0), WW - 1);                    // v_sub + v_med3
        float v = semb[wid][d] + (float)mm[j] * (-1e9f);
        p[j] = __expf(v);
        s += p[j];
    }

    // Wave-wide sum: DPP chain, total in lane 63, broadcast via readlane.
    s = dpp_add_step<0x111>(s);   // row_shr:1
    s = dpp_add_step<0x112>(s);   // row_shr:2
    s = dpp_add_step<0x114>(s);   // row_shr:4
    s = dpp_add_step<0x118>(s);   // row_shr:8
    s = dpp_add_step<0x142>(s);   // row_bcast:15
    s = dpp_add_step<0x143>(s);   // row_bcast:31
    const float stot = __int_as_float(__builtin_amdgcn_readlane(__float_as_int(s), 63));

    const float inv = __builtin_amdgcn_rcpf(stot);
    vfloat4 o0 = {p[0] * inv, p[1] * inv, p[2] * inv, p[3] * inv};
    vfloat4 o1 = {p[4] * inv, p[5] * inv, p[6] * inv, p[7] * inv};

    // nt stores (R8 vs R9 A/B: nt wins by ~1.3us). Fully-contiguous 1KB bursts.
    const long obase = (long)row * CC + lane * 4;
    __builtin_nontemporal_store(o0, (vfloat4*)(out + obase));
    __builtin_nontemporal_store(o1, (vfloat4*)(out + obase + 256));
}

extern "C" void kernel_launch(void* const* d_in, const int* in_sizes, int n_in,
                              void* d_out, int out_size, void* d_ws, size_t ws_size,
                              hipStream_t stream) {
    const int*   concepts = (const int*)d_in[0];
    const int*   tts      = (const int*)d_in[1];
    const int*   cts      = (const int*)d_in[2];
    const int*   mask     = (const int*)d_in[3];
    const float* emb      = (const float*)d_in[4];
    float*       out      = (float*)d_out;

    const int blocks = ROWS / 4;   // 8192 blocks, 4 waves (rows) each
    TimeAttention_38345468019460_kernel<<<blocks, 256, 0, stream>>>(
        concepts, tts, cts, mask, emb, out);
}